// Round 2
// baseline (728.714 us; speedup 1.0000x reference)
//
#include <hip/hip_runtime.h>

#define IN_DIM 4096
#define OUT_DIM 4096
#define N_ROWS 8192
#define RANK 256

typedef __bf16 bf16x8 __attribute__((ext_vector_type(8)));
typedef float f32x4 __attribute__((ext_vector_type(4)));
typedef unsigned short u16;

__device__ __forceinline__ u16 f2b(float f) {
    unsigned int u = __builtin_bit_cast(unsigned int, f);
    unsigned int r = u + 0x7FFFu + ((u >> 16) & 1u);
    return (u16)(r >> 16);
}

__device__ __forceinline__ void async16(const void* g, const void* l) {
    __builtin_amdgcn_global_load_lds(
        (const __attribute__((address_space(1))) void*)g,
        (__attribute__((address_space(3))) void*)l, 16, 0, 0);
}

// fp32 -> bf16 bulk convert, 4 elems/thread, fully coalesced.
__global__ __launch_bounds__(256) void cvt4(const float* __restrict__ s,
                                            u16* __restrict__ d, int n4) {
    int i = blockIdx.x * 256 + threadIdx.x;
    if (i >= n4) return;
    float4 v = ((const float4*)s)[i];
    ushort4 o;
    o.x = f2b(v.x); o.y = f2b(v.y); o.z = f2b(v.z); o.w = f2b(v.w);
    ((ushort4*)d)[i] = o;
}

// AdT[i][r] = bf16(d[r] * A[r][i]).  thread = r (256 threads), block covers
// 64 consecutive i. Writes are contiguous 512B rows; reads stream per-thread.
__global__ __launch_bounds__(256) void vera_adt(const float* __restrict__ A,
                                                const float* __restrict__ d,
                                                u16* __restrict__ adt) {
    int r = threadIdx.x;
    int i0 = blockIdx.x * 64;
    float dv = d[r];
    const float* ap = A + (size_t)r * IN_DIM + i0;
#pragma unroll 4
    for (int j = 0; j < 64; ++j)
        adt[(size_t)(i0 + j) * RANK + r] = f2b(ap[j] * dv);
}

// C = Aop · Bop^T, both bf16 row-major [rows][K] (K-contiguous). m97 structure:
// 128x128 tile, BK=32, 256 threads = 4 waves (2x2), each wave 4x4 of 16x16x32.
// MODE 0: out(u16)[row][col] = bf16(W[row][col] + bvec[row] * acc)  (W_eff)
// MODE 1: out(f32)[row][col] = acc + bvec[col]                      (main+bias)
template <int MODE>
__global__ __launch_bounds__(256) void vera_gemm(
    const u16* __restrict__ Aop, const u16* __restrict__ Bop,
    const float* __restrict__ W, const float* __restrict__ bvec,
    void* __restrict__ outv, int Nn, int K) {
    __shared__ __align__(16) __bf16 As[128 * 32];
    __shared__ __align__(16) __bf16 Bs[128 * 32];

    const int tid = threadIdx.x;
    const int lane = tid & 63;
    const int wavei = __builtin_amdgcn_readfirstlane(tid >> 6);
    const int fr = lane & 15;   // A/B frag row; C col
    const int fq = lane >> 4;   // quad
    const int wm = (wavei >> 1) * 64;
    const int wn = (wavei & 1) * 64;

    const int bm = blockIdx.y * 128;
    const int bn = blockIdx.x * 128;

    // staging: thread t loads 16B (8 bf16): row = t/4 (+64 on 2nd call), k=(t%4)*8
    const int srow = tid >> 2;
    const int sk = (tid & 3) * 8;
    const u16* ga0 = Aop + (size_t)(bm + srow) * K + sk;
    const u16* ga1 = Aop + (size_t)(bm + 64 + srow) * K + sk;
    const u16* gb0 = Bop + (size_t)(bn + srow) * K + sk;
    const u16* gb1 = Bop + (size_t)(bn + 64 + srow) * K + sk;

    char* lAs = (char*)As;
    char* lBs = (char*)Bs;
    const int lo = wavei * 1024;   // wave-uniform LDS base; HW adds lane*16

    f32x4 acc[4][4] = {};

    for (int k0 = 0; k0 < K; k0 += 32) {
        __syncthreads();
        async16(ga0 + k0, lAs + lo);
        async16(ga1 + k0, lAs + 4096 + lo);
        async16(gb0 + k0, lBs + lo);
        async16(gb1 + k0, lBs + 4096 + lo);
        __syncthreads();

        const __bf16* ap = As + (wm + fr) * 32 + fq * 8;
        const __bf16* bp = Bs + (wn + fr) * 32 + fq * 8;
        bf16x8 af[4], bfr[4];
#pragma unroll
        for (int i = 0; i < 4; ++i) {
            af[i] = *(const bf16x8*)(ap + i * 16 * 32);
            bfr[i] = *(const bf16x8*)(bp + i * 16 * 32);
        }
#pragma unroll
        for (int mi = 0; mi < 4; ++mi)
#pragma unroll
            for (int ni = 0; ni < 4; ++ni)
                acc[mi][ni] = __builtin_amdgcn_mfma_f32_16x16x32_bf16(
                    af[mi], bfr[ni], acc[mi][ni], 0, 0, 0);
    }

    // C/D layout (m89-verified): col = lane&15, row = (lane>>4)*4 + reg
#pragma unroll
    for (int ni = 0; ni < 4; ++ni) {
        const int col = bn + wn + ni * 16 + fr;
        float bcol = (MODE == 1) ? bvec[col] : 0.f;
#pragma unroll
        for (int mi = 0; mi < 4; ++mi) {
            const int row0 = bm + wm + mi * 16 + fq * 4;
#pragma unroll
            for (int v = 0; v < 4; ++v) {
                const int row = row0 + v;
                float a = acc[mi][ni][v];
                if (MODE == 0) {
                    float wv = W[(size_t)row * Nn + col];
                    ((u16*)outv)[(size_t)row * Nn + col] = f2b(wv + bvec[row] * a);
                } else {
                    ((float*)outv)[(size_t)row * Nn + col] = a + bcol;
                }
            }
        }
    }
}

extern "C" void kernel_launch(void* const* d_in, const int* in_sizes, int n_in,
                              void* d_out, int out_size, void* d_ws, size_t ws_size,
                              hipStream_t stream) {
    (void)in_sizes; (void)n_in; (void)out_size; (void)ws_size;
    const float* x    = (const float*)d_in[0];   // [N, IN]
    const float* W    = (const float*)d_in[1];   // [OUT, IN]
    const float* bias = (const float*)d_in[2];   // [OUT]
    const float* A    = (const float*)d_in[3];   // [RANK, IN]
    const float* B    = (const float*)d_in[4];   // [OUT, RANK]
    const float* bv   = (const float*)d_in[5];   // [OUT]
    const float* dv   = (const float*)d_in[6];   // [RANK]

    char* ws = (char*)d_ws;
    u16* xb  = (u16*)ws;                                          // 64 MiB
    u16* wb  = (u16*)(ws + (size_t)N_ROWS * IN_DIM * 2);          // 32 MiB
    u16* adt = (u16*)(ws + (size_t)N_ROWS * IN_DIM * 2
                         + (size_t)OUT_DIM * IN_DIM * 2);         // 2 MiB
    u16* Bb  = adt + (size_t)IN_DIM * RANK;                       // 2 MiB

    // 1) x -> bf16
    cvt4<<<dim3(N_ROWS * IN_DIM / 4 / 256), 256, 0, stream>>>(x, xb, N_ROWS * IN_DIM / 4);
    // 2) B -> bf16
    cvt4<<<dim3(OUT_DIM * RANK / 4 / 256), 256, 0, stream>>>(B, Bb, OUT_DIM * RANK / 4);
    // 3) AdT = (diag(d) A)^T, bf16
    vera_adt<<<dim3(IN_DIM / 64), 256, 0, stream>>>(A, dv, adt);
    // 4) W_eff = W + diag(b) · B · AdT^T   (M=OUT, N=IN, K=RANK)
    vera_gemm<0><<<dim3(IN_DIM / 128, OUT_DIM / 128), 256, 0, stream>>>(
        Bb, adt, W, bv, wb, IN_DIM, RANK);
    // 5) out = x · W_eff^T + bias          (M=N_ROWS, N=OUT, K=IN), fp32 out
    vera_gemm<1><<<dim3(OUT_DIM / 128, N_ROWS / 128), 256, 0, stream>>>(
        xb, wb, nullptr, bias, d_out, OUT_DIM, IN_DIM);
}

// Round 4
// 608.916 us; speedup vs baseline: 1.1967x; 1.1967x over previous
//
#include <hip/hip_runtime.h>

#define IN_DIM 4096
#define OUT_DIM 4096
#define N_ROWS 8192
#define RANK 256

typedef __bf16 bf16x8 __attribute__((ext_vector_type(8)));
typedef float f32x4 __attribute__((ext_vector_type(4)));
typedef unsigned short u16;
typedef unsigned short u16x4 __attribute__((ext_vector_type(4)));

__device__ __forceinline__ u16 f2b(float f) {
    unsigned int u = __builtin_bit_cast(unsigned int, f);
    unsigned int r = u + 0x7FFFu + ((u >> 16) & 1u);
    return (u16)(r >> 16);
}

__device__ __forceinline__ void async16(const void* g, const void* l) {
    __builtin_amdgcn_global_load_lds(
        (const __attribute__((address_space(1))) void*)g,
        (__attribute__((address_space(3))) void*)l, 16, 0, 0);
}

// fp32 -> bf16 bulk convert, 4 elems/thread, coalesced. nt loads: source is
// read exactly once; keep it out of LLC so bf16 scratch stays resident.
__global__ __launch_bounds__(256) void cvt4(const float* __restrict__ s,
                                            u16* __restrict__ d, int n4) {
    int i = blockIdx.x * 256 + threadIdx.x;
    if (i >= n4) return;
    f32x4 v = __builtin_nontemporal_load((const f32x4*)s + i);
    u16x4 o;
    o.x = f2b(v.x); o.y = f2b(v.y); o.z = f2b(v.z); o.w = f2b(v.w);
    *((u16x4*)d + i) = o;
}

// AdT[i][r] = bf16(d[r] * A[r][i]).  thread = r (256 threads), block covers
// 64 consecutive i. Writes contiguous 512B rows; A read once (nt).
__global__ __launch_bounds__(256) void vera_adt(const float* __restrict__ A,
                                                const float* __restrict__ d,
                                                u16* __restrict__ adt) {
    int r = threadIdx.x;
    int i0 = blockIdx.x * 64;
    float dv = d[r];
    const float* ap = A + (size_t)r * IN_DIM + i0;
#pragma unroll 4
    for (int j = 0; j < 64; ++j)
        adt[(size_t)(i0 + j) * RANK + r] = f2b(__builtin_nontemporal_load(ap + j) * dv);
}

// C = Aop · Bop^T, both bf16 row-major [rows][K] (K-contiguous). m97 structure:
// 128x128 tile, BK=32, 256 threads = 4 waves (2x2), each wave 4x4 of 16x16x32.
// 1D grid, swizzled: groups of G=8 M-tiles iterate fastest so co-resident
// blocks share B-operand (W_eff) slabs in L2/LLC.
// MODE 0: out(u16)[row][col] = bf16(W[row][col] + bvec[row] * acc)  (W_eff)
// MODE 1: out(f32)[row][col] = acc + bvec[col], nt store             (main+bias)
template <int MODE, int K, int NN, int TM, int TN>
__global__ __launch_bounds__(256) void vera_gemm(
    const u16* __restrict__ Aop, const u16* __restrict__ Bop,
    const float* __restrict__ W, const float* __restrict__ bvec,
    void* __restrict__ outv) {
    __shared__ __align__(16) __bf16 As[128 * 32];
    __shared__ __align__(16) __bf16 Bs[128 * 32];

    const int tid = threadIdx.x;
    const int lane = tid & 63;
    const int wavei = __builtin_amdgcn_readfirstlane(tid >> 6);
    const int fr = lane & 15;   // A/B frag row; C col
    const int fq = lane >> 4;   // quad
    const int wm = (wavei >> 1) * 64;
    const int wn = (wavei & 1) * 64;

    // swizzle: G M-tiles innermost, then N-tiles, then group
    constexpr int G = 8;
    const int bid = blockIdx.x;
    const int g = bid / (G * TN);
    const int r = bid - g * (G * TN);
    const int bm = (g * G + (r & (G - 1))) * 128;
    const int bn = (r / G) * 128;

    // staging: thread t loads 16B (8 bf16): row = t/4 (+64 on 2nd call), k=(t%4)*8
    const int srow = tid >> 2;
    const int sk = (tid & 3) * 8;
    const u16* ga0 = Aop + (size_t)(bm + srow) * K + sk;
    const u16* ga1 = Aop + (size_t)(bm + 64 + srow) * K + sk;
    const u16* gb0 = Bop + (size_t)(bn + srow) * K + sk;
    const u16* gb1 = Bop + (size_t)(bn + 64 + srow) * K + sk;

    char* lAs = (char*)As;
    char* lBs = (char*)Bs;
    const int lo = wavei * 1024;   // wave-uniform LDS base; HW adds lane*16

    f32x4 acc[4][4] = {};

    for (int k0 = 0; k0 < K; k0 += 32) {
        __syncthreads();
        async16(ga0 + k0, lAs + lo);
        async16(ga1 + k0, lAs + 4096 + lo);
        async16(gb0 + k0, lBs + lo);
        async16(gb1 + k0, lBs + 4096 + lo);
        __syncthreads();

        const __bf16* ap = As + (wm + fr) * 32 + fq * 8;
        const __bf16* bp = Bs + (wn + fr) * 32 + fq * 8;
        bf16x8 af[4], bfr[4];
#pragma unroll
        for (int i = 0; i < 4; ++i) {
            af[i] = *(const bf16x8*)(ap + i * 16 * 32);
            bfr[i] = *(const bf16x8*)(bp + i * 16 * 32);
        }
#pragma unroll
        for (int mi = 0; mi < 4; ++mi)
#pragma unroll
            for (int ni = 0; ni < 4; ++ni)
                acc[mi][ni] = __builtin_amdgcn_mfma_f32_16x16x32_bf16(
                    af[mi], bfr[ni], acc[mi][ni], 0, 0, 0);
    }

    // C/D layout (m89-verified): col = lane&15, row = (lane>>4)*4 + reg
#pragma unroll
    for (int ni = 0; ni < 4; ++ni) {
        const int col = bn + wn + ni * 16 + fr;
        float bcol = (MODE == 1) ? bvec[col] : 0.f;
#pragma unroll
        for (int mi = 0; mi < 4; ++mi) {
            const int row0 = bm + wm + mi * 16 + fq * 4;
#pragma unroll
            for (int v = 0; v < 4; ++v) {
                const int row = row0 + v;
                float a = acc[mi][ni][v];
                if (MODE == 0) {
                    // W read once (nt); wb re-read by main GEMM -> normal store
                    float wv = __builtin_nontemporal_load(&W[(size_t)row * NN + col]);
                    ((u16*)outv)[(size_t)row * NN + col] = f2b(wv + bvec[row] * a);
                } else {
                    // d_out never re-read: nt store keeps x/W_eff LLC-resident
                    __builtin_nontemporal_store(a + bcol,
                        &((float*)outv)[(size_t)row * NN + col]);
                }
            }
        }
    }
}

extern "C" void kernel_launch(void* const* d_in, const int* in_sizes, int n_in,
                              void* d_out, int out_size, void* d_ws, size_t ws_size,
                              hipStream_t stream) {
    (void)in_sizes; (void)n_in; (void)out_size; (void)ws_size;
    const float* x    = (const float*)d_in[0];   // [N, IN]
    const float* W    = (const float*)d_in[1];   // [OUT, IN]
    const float* bias = (const float*)d_in[2];   // [OUT]
    const float* A    = (const float*)d_in[3];   // [RANK, IN]
    const float* B    = (const float*)d_in[4];   // [OUT, RANK]
    const float* bv   = (const float*)d_in[5];   // [OUT]
    const float* dv   = (const float*)d_in[6];   // [RANK]

    char* ws = (char*)d_ws;
    u16* xb  = (u16*)ws;                                          // 64 MiB
    u16* wb  = (u16*)(ws + (size_t)N_ROWS * IN_DIM * 2);          // 32 MiB
    u16* adt = (u16*)(ws + (size_t)N_ROWS * IN_DIM * 2
                         + (size_t)OUT_DIM * IN_DIM * 2);         // 2 MiB
    u16* Bb  = adt + (size_t)IN_DIM * RANK;                       // 2 MiB

    // 1) B -> bf16
    cvt4<<<dim3(OUT_DIM * RANK / 4 / 256), 256, 0, stream>>>(B, Bb, OUT_DIM * RANK / 4);
    // 2) AdT = (diag(d) A)^T, bf16
    vera_adt<<<dim3(IN_DIM / 64), 256, 0, stream>>>(A, dv, adt);
    // 3) W_eff = W + diag(b) · B · AdT^T   (M=OUT, N=IN, K=RANK)
    vera_gemm<0, RANK, IN_DIM, OUT_DIM / 128, IN_DIM / 128>
        <<<dim3((OUT_DIM / 128) * (IN_DIM / 128)), 256, 0, stream>>>(
        Bb, adt, W, bv, wb);
    // 4) x -> bf16
    cvt4<<<dim3(N_ROWS * IN_DIM / 4 / 256), 256, 0, stream>>>(x, xb, N_ROWS * IN_DIM / 4);
    // 5) out = x · W_eff^T + bias          (M=N_ROWS, N=OUT, K=IN), fp32 nt out
    vera_gemm<1, IN_DIM, OUT_DIM, N_ROWS / 128, OUT_DIM / 128>
        <<<dim3((N_ROWS / 128) * (OUT_DIM / 128)), 256, 0, stream>>>(
        xb, wb, nullptr, bias, d_out);
}